// Round 2
// baseline (5967.415 us; speedup 1.0000x reference)
//
#include <hip/hip_runtime.h>
#include <cstdint>

#define BB 256
#define TT 4096
#define FDIM 16
#define HH 128

typedef unsigned long long u64;

// ---------------------------------------------------------------------------
// Kernel 1: delta encoding -> 32-bit spike masks per (b, t).
// bits 0..15 = ON (feature f), bits 16..31 = OFF. Exact compares only.
// One wave per 4 batches (sub = lane>>4, f = lane&15).
// Input staged through a double-buffered LDS tile (64 timesteps) with
// coalesced float4 global loads prefetched one tile ahead, so the serial
// scan chain (~15 cy/step) is not exposed to HBM/L2 latency per step.
// ---------------------------------------------------------------------------
__global__ __launch_bounds__(64) void snn_encode(const float* __restrict__ x,
                                                 uint32_t* __restrict__ masks) {
  __shared__ float tile[2][4][64][16];  // 32 KiB
  const int lane = threadIdx.x;
  const int sub = lane >> 4;
  const int f = lane & 15;
  const int b0 = blockIdx.x * 4;
  float ref = x[(size_t)(b0 + sub) * (TT * FDIM) + f];

  const float4* xv = (const float4*)x;
  float4 ld[16];  // 16 float4/lane = one 4-batch x 64-step tile
#define K1_ISSUE(G)                                                           \
  _Pragma("unroll") for (int k = 0; k < 16; ++k) {                            \
    int idx4 = k * 64 + lane;                                                 \
    int bl = idx4 >> 8;                                                       \
    int r = idx4 & 255;                                                       \
    ld[k] = xv[(size_t)(b0 + bl) * (TT * 4) + (size_t)(G) * 256 + r];         \
  }
#define K1_WRITE(BUF)                                                         \
  _Pragma("unroll") for (int k = 0; k < 16; ++k) {                            \
    int idx4 = k * 64 + lane;                                                 \
    int bl = idx4 >> 8;                                                       \
    int r = idx4 & 255;                                                       \
    ((float4*)&tile[BUF][bl][0][0])[r] = ld[k];                               \
  }

  K1_ISSUE(0);
  K1_WRITE(0);
  for (int g = 0; g < TT / 64; ++g) {
    if (g + 1 < TT / 64) K1_ISSUE(g + 1);  // prefetch next tile into regs
    const int t0 = g * 64;
    const int buf = g & 1;
    for (int tt = 0; tt < 64; ++tt) {
      float cur = tile[buf][sub][tt][f];
      float diff = cur - ref;
      bool on = diff >= 0.5f;
      bool off = diff <= -0.5f;
      u64 bon = __ballot(on);
      u64 boff = __ballot(off);
      if (on || off) ref = cur;  // exact ref update (t=0 gives mask 0)
      if (f == 0) {
        uint32_t mk = (uint32_t)((bon >> (sub * 16)) & 0xFFFFull) |
                      ((uint32_t)((boff >> (sub * 16)) & 0xFFFFull) << 16);
        masks[(size_t)(b0 + sub) * TT + (t0 + tt)] = mk;
      }
    }
    if (g + 1 < TT / 64) K1_WRITE((g + 1) & 1);  // vmcnt wait lands here
  }
#undef K1_ISSUE
#undef K1_WRITE
}

// 64-lane sum via DPP — kept bit-identical to the passing round-1 kernel.
__device__ __forceinline__ float wave_red_add(float v) {
#define DPP_ADD(c)                                                             \
  v += __int_as_float(                                                         \
      __builtin_amdgcn_update_dpp(0, __float_as_int(v), c, 0xF, 0xF, true))
  DPP_ADD(0x111);  // row_shr:1
  DPP_ADD(0x112);  // row_shr:2
  DPP_ADD(0x114);  // row_shr:4
  DPP_ADD(0x118);  // row_shr:8
  DPP_ADD(0x142);  // row_bcast:15
  DPP_ADD(0x143);  // row_bcast:31
#undef DPP_ADD
  return __int_as_float(__builtin_amdgcn_readlane(__float_as_int(v), 63));
}

// ---------------------------------------------------------------------------
// Kernel 2: serial SNN core, one wave per batch (256 blocks = 256 CUs).
// Changes vs round 1 (all value-preserving, same add order):
//  - float2-paired weight columns: one ds_read_b64 feeds both neurons a
//    lane owns (h=lane, h=64+lane) -> half the LDS instructions.
//  - L1: branchless grab-16 (<=16 set bits guaranteed): 16 loads issue
//    together, conditional adds in ascending-j order. Dummy loads (j=0)
//    are never accumulated.
//  - L2: grab-8 groups per 64-bit half: latency paid per group, not per bit.
//  - Masks prefetched 8 steps ahead (uniform uint4); L1 loads for step t+1
//    issued before step t's L2 (depend only on masks -> depth-2 pipeline).
// ---------------------------------------------------------------------------
__global__ __launch_bounds__(64) void snn_core2(
    const uint32_t* __restrict__ masks, const float* __restrict__ W1,
    const float* __restrict__ b1, const float* __restrict__ W2,
    const float* __restrict__ b2, const float* __restrict__ W3,
    const float* __restrict__ b3, float* __restrict__ out) {
  __shared__ float2 W1p[32 * 64];   // 16 KiB: [j][l] = (W1[l][j], W1[64+l][j])
  __shared__ float2 W2p[128 * 64];  // 64 KiB: [j][l] = (W2[l][j], W2[64+l][j])
  const int lane = threadIdx.x;
  const int b = blockIdx.x;

  // Coalesced global reads (consecutive j, fixed l per 64-lane row);
  // one-time conflicted LDS writes are noise.
#pragma unroll 4
  for (int i = lane; i < 32 * 64; i += 64) {
    int l = i >> 5, j = i & 31;
    W1p[j * 64 + l] = make_float2(W1[l * 32 + j], W1[(64 + l) * 32 + j]);
  }
#pragma unroll 4
  for (int i = lane; i < 128 * 64; i += 64) {
    int l = i >> 7, j = i & 127;
    W2p[j * 64 + l] = make_float2(W2[l * 128 + j], W2[(64 + l) * 128 + j]);
  }
  const float b1a = b1[lane], b1b = b1[64 + lane];
  const float b2a = b2[lane], b2b = b2[64 + lane];
  const float w30a = W3[lane], w30b = W3[64 + lane];
  const float w31a = W3[128 + lane], w31b = W3[192 + lane];
  const float b30 = b3[0], b31 = b3[1];
  __syncthreads();

  float m1a = 0.f, m1b = 0.f, m2a = 0.f, m2b = 0.f, m3x = 0.f, m3y = 0.f;
  const uint4* mp4 = (const uint4*)(masks + (size_t)b * TT);
  float2* outv = (float2*)out;

  // L1 current from mask MSK (<=16 bits). Branchless grab-16: all loads
  // issue back-to-back; adds ascending-j, skipped when invalid.
#define L1SUM(MSK, A0, A1)                                                    \
  {                                                                           \
    uint32_t m_ = (MSK);                                                      \
    A0 = 0.f;                                                                 \
    A1 = 0.f;                                                                 \
    _Pragma("unroll") for (int k = 0; k < 16; ++k) {                          \
      bool v_ = (m_ != 0);                                                    \
      int j_ = v_ ? __builtin_ctz(m_) : 0;                                    \
      m_ &= m_ - 1;                                                           \
      float2 w_ = W1p[j_ * 64 + lane];                                        \
      if (v_) {                                                               \
        A0 += w_.x;                                                           \
        A1 += w_.y;                                                           \
      }                                                                       \
    }                                                                         \
  }

  // L2 sparse column sum over a 64-bit half-mask, 8 bits per group.
#define L2HALF(MASK64, BASE, C0, C1)                                          \
  {                                                                           \
    u64 m_ = (MASK64);                                                        \
    while (m_) {                                                              \
      int j0 = __builtin_ctzll(m_); m_ &= m_ - 1;                             \
      bool v1 = m_ != 0; int j1 = v1 ? __builtin_ctzll(m_) : 0; m_ &= m_ - 1; \
      bool v2 = m_ != 0; int j2 = v2 ? __builtin_ctzll(m_) : 0; m_ &= m_ - 1; \
      bool v3 = m_ != 0; int j3 = v3 ? __builtin_ctzll(m_) : 0; m_ &= m_ - 1; \
      bool v4 = m_ != 0; int j4 = v4 ? __builtin_ctzll(m_) : 0; m_ &= m_ - 1; \
      bool v5 = m_ != 0; int j5 = v5 ? __builtin_ctzll(m_) : 0; m_ &= m_ - 1; \
      bool v6 = m_ != 0; int j6 = v6 ? __builtin_ctzll(m_) : 0; m_ &= m_ - 1; \
      bool v7 = m_ != 0; int j7 = v7 ? __builtin_ctzll(m_) : 0; m_ &= m_ - 1; \
      float2 w0 = W2p[((BASE) + j0) * 64 + lane];                             \
      float2 w1 = W2p[((BASE) + j1) * 64 + lane];                             \
      float2 w2 = W2p[((BASE) + j2) * 64 + lane];                             \
      float2 w3 = W2p[((BASE) + j3) * 64 + lane];                             \
      float2 w4 = W2p[((BASE) + j4) * 64 + lane];                             \
      float2 w5 = W2p[((BASE) + j5) * 64 + lane];                             \
      float2 w6 = W2p[((BASE) + j6) * 64 + lane];                             \
      float2 w7 = W2p[((BASE) + j7) * 64 + lane];                             \
      C0 += w0.x; C1 += w0.y;                                                 \
      if (v1) { C0 += w1.x; C1 += w1.y; }                                     \
      if (v2) { C0 += w2.x; C1 += w2.y; }                                     \
      if (v3) { C0 += w3.x; C1 += w3.y; }                                     \
      if (v4) { C0 += w4.x; C1 += w4.y; }                                     \
      if (v5) { C0 += w5.x; C1 += w5.y; }                                     \
      if (v6) { C0 += w6.x; C1 += w6.y; }                                     \
      if (v7) { C0 += w7.x; C1 += w7.y; }                                     \
    }                                                                         \
  }

  // One LIF step for time T. Consumes carried acc0/acc1 (L1 sum of step T),
  // precomputes next step's L1 sum from MSK_NEXT (issues its LDS loads early
  // so they fly under this step's L2 work).
#define STEP(MSK_NEXT, T)                                                     \
  {                                                                           \
    float na0, na1;                                                           \
    L1SUM(MSK_NEXT, na0, na1);                                                \
    float cur0 = acc0 + b1a, cur1 = acc1 + b1b;                               \
    float n0 = __fadd_rn(__fmul_rn(0.9f, m1a), cur0);                         \
    float n1 = __fadd_rn(__fmul_rn(0.9f, m1b), cur1);                         \
    m1a = (m1a > 1.f) ? (n0 - 1.f) : n0;                                      \
    m1b = (m1b > 1.f) ? (n1 - 1.f) : n1;                                      \
    u64 s0 = __ballot(m1a > 1.f);                                             \
    u64 s1 = __ballot(m1b > 1.f);                                             \
    float c0 = 0.f, c1 = 0.f;                                                 \
    L2HALF(s0, 0, c0, c1);                                                    \
    L2HALF(s1, 64, c0, c1);                                                   \
    c0 += b2a;                                                                \
    c1 += b2b;                                                                \
    float u0 = __fadd_rn(__fmul_rn(0.9f, m2a), c0);                           \
    float u1 = __fadd_rn(__fmul_rn(0.9f, m2b), c1);                           \
    m2a = (m2a > 1.f) ? (u0 - 1.f) : u0;                                      \
    m2b = (m2b > 1.f) ? (u1 - 1.f) : u1;                                      \
    bool q0 = m2a > 1.f;                                                      \
    bool q1 = m2b > 1.f;                                                      \
    float p0 = (q0 ? w30a : 0.f) + (q1 ? w30b : 0.f);                         \
    float p1 = (q0 ? w31a : 0.f) + (q1 ? w31b : 0.f);                         \
    float cur3x = wave_red_add(p0) + b30;                                     \
    float cur3y = wave_red_add(p1) + b31;                                     \
    float e0 = __fadd_rn(__fmul_rn(0.9f, m3x), cur3x);                        \
    float e1 = __fadd_rn(__fmul_rn(0.9f, m3y), cur3y);                        \
    m3x = (m3x > 1.f) ? (e0 - 1.f) : e0;                                      \
    m3y = (m3y > 1.f) ? (e1 - 1.f) : e1;                                      \
    if (lane == 0) outv[(size_t)(T)*BB + b] = make_float2(m3x, m3y);          \
    acc0 = na0;                                                               \
    acc1 = na1;                                                               \
  }

  // Prologue: L1 sum for t=0.
  float acc0, acc1;
  {
    uint32_t mk0 = masks[(size_t)b * TT];
    L1SUM(mk0, acc0, acc1);
  }
  uint4 ca = mp4[0], cb = mp4[1];  // masks[t0..t0+3], [t0+4..t0+7]
  for (int t0 = 0; t0 < TT; t0 += 8) {
    int tn = (t0 + 8) & (TT - 1);
    uint4 na = mp4[tn >> 2];        // prefetch next 8 masks
    uint4 nb = mp4[(tn >> 2) + 1];
    STEP(ca.y, t0 + 0);
    STEP(ca.z, t0 + 1);
    STEP(ca.w, t0 + 2);
    STEP(cb.x, t0 + 3);
    STEP(cb.y, t0 + 4);
    STEP(cb.z, t0 + 5);
    STEP(cb.w, t0 + 6);
    STEP(na.x, t0 + 7);  // mask[t0+8]
    ca = na;
    cb = nb;
  }
#undef STEP
#undef L2HALF
#undef L1SUM
}

extern "C" void kernel_launch(void* const* d_in, const int* in_sizes, int n_in,
                              void* d_out, int out_size, void* d_ws,
                              size_t ws_size, hipStream_t stream) {
  const float* x = (const float*)d_in[0];
  const float* W1 = (const float*)d_in[1];
  const float* b1 = (const float*)d_in[2];
  const float* W2 = (const float*)d_in[3];
  const float* b2 = (const float*)d_in[4];
  const float* W3 = (const float*)d_in[5];
  const float* b3 = (const float*)d_in[6];
  float* out = (float*)d_out;
  uint32_t* masks = (uint32_t*)d_ws;  // B*T*4 = 4 MiB of workspace

  snn_encode<<<BB / 4, 64, 0, stream>>>(x, masks);
  snn_core2<<<BB, 64, 0, stream>>>(masks, W1, b1, W2, b2, W3, b3, out);
}

// Round 3
// 4719.123 us; speedup vs baseline: 1.2645x; 1.2645x over previous
//
#include <hip/hip_runtime.h>
#include <cstdint>

#define BB 256
#define TT 4096
#define FDIM 16
#define HH 128

typedef unsigned long long u64;
typedef float f32x2 __attribute__((ext_vector_type(2)));

// Packed fp32 add: d.lo = a.lo+b.lo, d.hi = a.hi+b.hi (IEEE rn, same as two
// scalar v_add_f32). Dataflow (acc feeds next add) pins the association, so
// the summation order is bit-identical to the scalar chain it replaces.
__device__ __forceinline__ f32x2 pk_add(f32x2 a, f32x2 b) {
  f32x2 d;
  asm("v_pk_add_f32 %0, %1, %2" : "=v"(d) : "v"(a), "v"(b));
  return d;
}

// ---------------------------------------------------------------------------
// Kernel 1: delta encoding -> 32-bit spike masks per (b, t). Unchanged from
// the passing round-2 version (exact compares; one wave per 4 batches; input
// staged through a double-buffered LDS tile with float4 prefetch).
// ---------------------------------------------------------------------------
__global__ __launch_bounds__(64) void snn_encode(const float* __restrict__ x,
                                                 uint32_t* __restrict__ masks) {
  __shared__ float tile[2][4][64][16];  // 32 KiB
  const int lane = threadIdx.x;
  const int sub = lane >> 4;
  const int f = lane & 15;
  const int b0 = blockIdx.x * 4;
  float ref = x[(size_t)(b0 + sub) * (TT * FDIM) + f];

  const float4* xv = (const float4*)x;
  float4 ld[16];
#define K1_ISSUE(G)                                                           \
  _Pragma("unroll") for (int k = 0; k < 16; ++k) {                            \
    int idx4 = k * 64 + lane;                                                 \
    int bl = idx4 >> 8;                                                       \
    int r = idx4 & 255;                                                       \
    ld[k] = xv[(size_t)(b0 + bl) * (TT * 4) + (size_t)(G) * 256 + r];         \
  }
#define K1_WRITE(BUF)                                                         \
  _Pragma("unroll") for (int k = 0; k < 16; ++k) {                            \
    int idx4 = k * 64 + lane;                                                 \
    int bl = idx4 >> 8;                                                       \
    int r = idx4 & 255;                                                       \
    ((float4*)&tile[BUF][bl][0][0])[r] = ld[k];                               \
  }

  K1_ISSUE(0);
  K1_WRITE(0);
  for (int g = 0; g < TT / 64; ++g) {
    if (g + 1 < TT / 64) K1_ISSUE(g + 1);
    const int t0 = g * 64;
    const int buf = g & 1;
    for (int tt = 0; tt < 64; ++tt) {
      float cur = tile[buf][sub][tt][f];
      float diff = cur - ref;
      bool on = diff >= 0.5f;
      bool off = diff <= -0.5f;
      u64 bon = __ballot(on);
      u64 boff = __ballot(off);
      if (on || off) ref = cur;
      if (f == 0) {
        uint32_t mk = (uint32_t)((bon >> (sub * 16)) & 0xFFFFull) |
                      ((uint32_t)((boff >> (sub * 16)) & 0xFFFFull) << 16);
        masks[(size_t)(b0 + sub) * TT + (t0 + tt)] = mk;
      }
    }
    if (g + 1 < TT / 64) K1_WRITE((g + 1) & 1);
  }
#undef K1_ISSUE
#undef K1_WRITE
}

// 64-lane DPP sum; result valid in lane 63 (same op sequence as the passing
// round-1 kernel, readlane dropped -> consume in lane 63).
__device__ __forceinline__ float wave_red_add63(float v) {
#define DPP_ADD(c)                                                             \
  v += __int_as_float(                                                         \
      __builtin_amdgcn_update_dpp(0, __float_as_int(v), c, 0xF, 0xF, true))
  DPP_ADD(0x111);  // row_shr:1
  DPP_ADD(0x112);  // row_shr:2
  DPP_ADD(0x114);  // row_shr:4
  DPP_ADD(0x118);  // row_shr:8
  DPP_ADD(0x142);  // row_bcast:15
  DPP_ADD(0x143);  // row_bcast:31
#undef DPP_ADD
  return v;
}

// ---------------------------------------------------------------------------
// Kernel 2: serial SNN core, one wave per batch (256 blocks = 256 CUs).
// Round-3 structure: explicit batched load arrays + sentinel zero rows
// (unconditional strict-order add chains), packed f32 adds, L1(t+1) loads
// issued under L2(t), L3 DPP tail consumed in lane 63.
// ---------------------------------------------------------------------------
__global__ __launch_bounds__(64, 1) void snn_core3(
    const uint32_t* __restrict__ masks, const float* __restrict__ W1,
    const float* __restrict__ b1, const float* __restrict__ W2,
    const float* __restrict__ b2, const float* __restrict__ W3,
    const float* __restrict__ b3, float* __restrict__ out) {
  __shared__ f32x2 W1p[33 * 64];   // [j][l] = (W1[l][j], W1[64+l][j]); j=32 zero
  __shared__ f32x2 W2p[129 * 64];  // [j][l] = (W2[l][j], W2[64+l][j]); j=128 zero
  const int lane = threadIdx.x;
  const int b = blockIdx.x;

  // Coalesced global reads; one-time transposed LDS writes.
#pragma unroll 4
  for (int i = lane; i < 32 * 64; i += 64) {
    int l = i >> 5, j = i & 31;
    W1p[j * 64 + l] = f32x2{W1[l * 32 + j], W1[(64 + l) * 32 + j]};
  }
#pragma unroll 4
  for (int i = lane; i < 128 * 64; i += 64) {
    int l = i >> 7, j = i & 127;
    W2p[j * 64 + l] = f32x2{W2[l * 128 + j], W2[(64 + l) * 128 + j]};
  }
  W1p[32 * 64 + lane] = f32x2{0.f, 0.f};   // sentinel rows
  W2p[128 * 64 + lane] = f32x2{0.f, 0.f};
  const f32x2 bias1 = {b1[lane], b1[64 + lane]};
  const f32x2 bias2 = {b2[lane], b2[64 + lane]};
  const float w30a = W3[lane], w30b = W3[64 + lane];
  const float w31a = W3[128 + lane], w31b = W3[192 + lane];
  const float b30 = b3[0], b31 = b3[1];
  __syncthreads();

  float m1a = 0.f, m1b = 0.f, m2a = 0.f, m2b = 0.f, m3x = 0.f, m3y = 0.f;
  const uint4* mp4 = (const uint4*)(masks + (size_t)b * TT);
  float2* outv = (float2*)out;

  // Issue the 16 L1 column loads for mask MSK into WARR (<=16 set bits
  // guaranteed: on/off exclusive per feature). Invalid slots -> sentinel row.
#define L1_ISSUE(MSK, WARR)                                                   \
  {                                                                           \
    uint32_t m_ = (MSK);                                                      \
    _Pragma("unroll") for (int k = 0; k < 16; ++k) {                          \
      int j_ = m_ ? __builtin_ctz(m_) : 32;                                   \
      m_ &= m_ - 1;                                                           \
      WARR[k] = W1p[j_ * 64 + lane];                                          \
    }                                                                         \
  }

  f32x2 wL1[16];
  {
    uint32_t mk0 = masks[(size_t)b * TT];  // t=0 (reference encodes it as 0)
    L1_ISSUE(mk0, wL1);
  }

#define STEP(MSK_NEXT, T)                                                     \
  {                                                                           \
    /* (a) L1 accumulate (loads issued last step, long since landed) */       \
    f32x2 acc = {0.f, 0.f};                                                   \
    _Pragma("unroll") for (int k = 0; k < 16; ++k) acc = pk_add(acc, wL1[k]); \
    f32x2 cur1 = pk_add(acc, bias1);                                          \
    /* (b) LIF1 */                                                            \
    float n0 = __fadd_rn(__fmul_rn(0.9f, m1a), cur1.x);                       \
    float n1 = __fadd_rn(__fmul_rn(0.9f, m1b), cur1.y);                       \
    m1a = (m1a > 1.f) ? (n0 - 1.f) : n0;                                      \
    m1b = (m1b > 1.f) ? (n1 - 1.f) : n1;                                      \
    u64 s0 = __ballot(m1a > 1.f);                                             \
    u64 s1 = __ballot(m1b > 1.f);                                             \
    /* (c) L2 issue: 16 lowest bits per half, sentinel-padded */              \
    f32x2 wA[16], wB[16];                                                     \
    u64 m_ = s0;                                                              \
    _Pragma("unroll") for (int k = 0; k < 16; ++k) {                          \
      int j_ = m_ ? __builtin_ctzll(m_) : 128;                                \
      m_ &= m_ - 1;                                                           \
      wA[k] = W2p[j_ * 64 + lane];                                            \
    }                                                                         \
    u64 r0 = m_;                                                              \
    m_ = s1;                                                                  \
    _Pragma("unroll") for (int k = 0; k < 16; ++k) {                          \
      int j_ = m_ ? 64 + __builtin_ctzll(m_) : 128;                           \
      m_ &= m_ - 1;                                                           \
      wB[k] = W2p[j_ * 64 + lane];                                            \
    }                                                                         \
    u64 r1 = m_;                                                              \
    /* (d) L1 loads for next step fly under this step's L2 consume */         \
    L1_ISSUE(MSK_NEXT, wL1);                                                  \
    /* (e) L2 accumulate, strict ascending order (sentinels add +0.0) */      \
    f32x2 c2 = {0.f, 0.f};                                                    \
    _Pragma("unroll") for (int k = 0; k < 16; ++k) c2 = pk_add(c2, wA[k]);    \
    if (r0) {                                                                 \
      do {                                                                    \
        int j_ = __builtin_ctzll(r0);                                         \
        r0 &= r0 - 1;                                                         \
        c2 = pk_add(c2, W2p[j_ * 64 + lane]);                                 \
      } while (r0);                                                           \
    }                                                                         \
    _Pragma("unroll") for (int k = 0; k < 16; ++k) c2 = pk_add(c2, wB[k]);    \
    if (r1) {                                                                 \
      do {                                                                    \
        int j_ = __builtin_ctzll(r1);                                         \
        r1 &= r1 - 1;                                                         \
        c2 = pk_add(c2, W2p[(64 + j_) * 64 + lane]);                          \
      } while (r1);                                                           \
    }                                                                         \
    c2 = pk_add(c2, bias2);                                                   \
    /* (f) LIF2 */                                                            \
    float u0 = __fadd_rn(__fmul_rn(0.9f, m2a), c2.x);                         \
    float u1 = __fadd_rn(__fmul_rn(0.9f, m2b), c2.y);                         \
    m2a = (m2a > 1.f) ? (u0 - 1.f) : u0;                                      \
    m2b = (m2b > 1.f) ? (u1 - 1.f) : u1;                                      \
    bool q0 = m2a > 1.f;                                                      \
    bool q1 = m2b > 1.f;                                                      \
    /* (g) L3: per-lane partials, DPP sum into lane 63, LIF3, store */        \
    float p0 = (q0 ? w30a : 0.f) + (q1 ? w30b : 0.f);                         \
    float p1 = (q0 ? w31a : 0.f) + (q1 ? w31b : 0.f);                         \
    float cur3x = wave_red_add63(p0) + b30;                                   \
    float cur3y = wave_red_add63(p1) + b31;                                   \
    float e0 = __fadd_rn(__fmul_rn(0.9f, m3x), cur3x);                        \
    float e1 = __fadd_rn(__fmul_rn(0.9f, m3y), cur3y);                        \
    m3x = (m3x > 1.f) ? (e0 - 1.f) : e0;                                      \
    m3y = (m3y > 1.f) ? (e1 - 1.f) : e1;                                      \
    if (lane == 63) outv[(size_t)(T)*BB + b] = make_float2(m3x, m3y);         \
  }

  uint4 ca = mp4[0], cb = mp4[1];
  for (int t0 = 0; t0 < TT; t0 += 8) {
    int tn = (t0 + 8) & (TT - 1);
    uint4 na = mp4[tn >> 2];
    uint4 nb = mp4[(tn >> 2) + 1];
    STEP(ca.y, t0 + 0);
    STEP(ca.z, t0 + 1);
    STEP(ca.w, t0 + 2);
    STEP(cb.x, t0 + 3);
    STEP(cb.y, t0 + 4);
    STEP(cb.z, t0 + 5);
    STEP(cb.w, t0 + 6);
    STEP(na.x, t0 + 7);
    ca = na;
    cb = nb;
  }
#undef STEP
#undef L1_ISSUE
}

extern "C" void kernel_launch(void* const* d_in, const int* in_sizes, int n_in,
                              void* d_out, int out_size, void* d_ws,
                              size_t ws_size, hipStream_t stream) {
  const float* x = (const float*)d_in[0];
  const float* W1 = (const float*)d_in[1];
  const float* b1 = (const float*)d_in[2];
  const float* W2 = (const float*)d_in[3];
  const float* b2 = (const float*)d_in[4];
  const float* W3 = (const float*)d_in[5];
  const float* b3 = (const float*)d_in[6];
  float* out = (float*)d_out;
  uint32_t* masks = (uint32_t*)d_ws;  // B*T*4 = 4 MiB of workspace

  snn_encode<<<BB / 4, 64, 0, stream>>>(x, masks);
  snn_core3<<<BB, 64, 0, stream>>>(masks, W1, b1, W2, b2, W3, b3, out);
}

// Round 4
// 4380.771 us; speedup vs baseline: 1.3622x; 1.0772x over previous
//
#include <hip/hip_runtime.h>
#include <cstdint>

#define BB 256
#define TT 4096
#define FDIM 16
#define HH 128

typedef unsigned long long u64;
typedef float f32x2 __attribute__((ext_vector_type(2)));
typedef uint32_t u32x4 __attribute__((ext_vector_type(4)));

// ---------------------------------------------------------------------------
// asm helpers. All loads are asm volatile => issue order == program order.
// After every wait: sched_barrier(0) (hipcc hoists reg-only consumers past
// inline-asm waitcnt otherwise — skill rule #18).
// ---------------------------------------------------------------------------
__device__ __forceinline__ uint32_t lds_addr32(const void* p) {
  // generic shared-space pointer: low 32 bits are the LDS byte offset
  return (uint32_t)(uintptr_t)p;
}
__device__ __forceinline__ f32x2 ds_read_b64_at(uint32_t addr) {
  f32x2 d;
  asm volatile("ds_read_b64 %0, %1" : "=v"(d) : "v"(addr));
  return d;
}
__device__ __forceinline__ f32x2 glb_load_b64(uint32_t voff, const void* base) {
  f32x2 d;
  asm volatile("global_load_dwordx2 %0, %1, %2" : "=v"(d) : "v"(voff), "s"(base));
  return d;
}
__device__ __forceinline__ u32x4 glb_load_b128(uint32_t voff, const void* base) {
  u32x4 d;
  asm volatile("global_load_dwordx4 %0, %1, %2" : "=v"(d) : "v"(voff), "s"(base));
  return d;
}
#define WAIT_LGKM(N)                                         \
  {                                                          \
    asm volatile("s_waitcnt lgkmcnt(" #N ")" ::: "memory");  \
    __builtin_amdgcn_sched_barrier(0);                       \
  }
#define WAIT_VM(N)                                           \
  {                                                          \
    asm volatile("s_waitcnt vmcnt(" #N ")" ::: "memory");    \
    __builtin_amdgcn_sched_barrier(0);                       \
  }
#define DS_READ_OFF(D, A, OFF) \
  asm volatile("ds_read_b32 %0, %1 offset:" #OFF : "=v"(D) : "v"(A));

// Packed fp32 add (two independent IEEE-rn adds; dataflow pins association).
__device__ __forceinline__ f32x2 pk_add(f32x2 a, f32x2 b) {
  f32x2 d;
  asm("v_pk_add_f32 %0, %1, %2" : "=v"(d) : "v"(a), "v"(b));
  return d;
}

// 64-lane DPP sum; result valid in lane 63 (same op sequence as rounds 1-3).
__device__ __forceinline__ float wave_red_add63(float v) {
#define DPP_ADD(c)                                                             \
  v += __int_as_float(                                                         \
      __builtin_amdgcn_update_dpp(0, __float_as_int(v), c, 0xF, 0xF, true))
  DPP_ADD(0x111);
  DPP_ADD(0x112);
  DPP_ADD(0x114);
  DPP_ADD(0x118);
  DPP_ADD(0x142);
  DPP_ADD(0x143);
#undef DPP_ADD
  return v;
}

// ---------------------------------------------------------------------------
// Kernel 0: build transposed W1 (+ zero sentinel row 32) in workspace.
// w1t[j][l] = (W1[l][j], W1[64+l][j]). 16.9 KB, stays L1$-resident for core.
// ---------------------------------------------------------------------------
__global__ __launch_bounds__(64) void snn_prep(const float* __restrict__ W1,
                                               f32x2* __restrict__ w1t) {
  const int l = threadIdx.x;
#pragma unroll
  for (int j = 0; j < 32; ++j)
    w1t[j * 64 + l] = f32x2{W1[l * 32 + j], W1[(64 + l) * 32 + j]};
  w1t[32 * 64 + l] = f32x2{0.f, 0.f};
}

// ---------------------------------------------------------------------------
// Kernel 1: delta encode -> 32-bit masks. 64 blocks x 1 wave x 4 batches.
// Scan reads are asm ds_read_b32 in chunks of 8 (offset: immediates), double-
// buffered with counted lgkmcnt(8). Tile staging (C-level ds_writes) fenced
// outside the counted region by "memory" waits.
// ---------------------------------------------------------------------------
__global__ __launch_bounds__(64) void snn_encode(const float* __restrict__ x,
                                                 uint32_t* __restrict__ masks) {
  __shared__ float tile[2][4][64][16];  // 32 KiB
  const int lane = threadIdx.x;
  const int sub = lane >> 4;
  const int f = lane & 15;
  const int b0 = blockIdx.x * 4;
  float ref = x[(size_t)(b0 + sub) * (TT * FDIM) + f];

  const float4* xv = (const float4*)x;
  float4 ld[16];
#define K1_ISSUE(G)                                                           \
  _Pragma("unroll") for (int k = 0; k < 16; ++k) {                            \
    int idx4 = k * 64 + lane;                                                 \
    int bl = idx4 >> 8;                                                       \
    int r = idx4 & 255;                                                       \
    ld[k] = xv[(size_t)(b0 + bl) * (TT * 4) + (size_t)(G) * 256 + r];         \
  }
#define K1_WRITE(BUF)                                                         \
  _Pragma("unroll") for (int k = 0; k < 16; ++k) {                            \
    int idx4 = k * 64 + lane;                                                 \
    int bl = idx4 >> 8;                                                       \
    int r = idx4 & 255;                                                       \
    ((float4*)&tile[BUF][bl][0][0])[r] = ld[k];                               \
  }
#define CHUNK_ISSUE(ARR, A)                                                   \
  {                                                                           \
    DS_READ_OFF(ARR[0], A, 0);                                                \
    DS_READ_OFF(ARR[1], A, 64);                                               \
    DS_READ_OFF(ARR[2], A, 128);                                              \
    DS_READ_OFF(ARR[3], A, 192);                                              \
    DS_READ_OFF(ARR[4], A, 256);                                              \
    DS_READ_OFF(ARR[5], A, 320);                                              \
    DS_READ_OFF(ARR[6], A, 384);                                              \
    DS_READ_OFF(ARR[7], A, 448);                                              \
  }
#define PROC8(ARR, TBASE)                                                     \
  _Pragma("unroll") for (int i = 0; i < 8; ++i) {                             \
    float cur = ARR[i];                                                       \
    float diff = cur - ref;                                                   \
    bool onb = diff >= 0.5f;                                                  \
    bool offb = diff <= -0.5f;                                                \
    u64 bon = __ballot(onb);                                                  \
    u64 boff = __ballot(offb);                                                \
    ref = (onb || offb) ? cur : ref;                                          \
    if (f == 0) {                                                             \
      uint32_t mk = (uint32_t)((bon >> (sub * 16)) & 0xFFFFull) |             \
                    ((uint32_t)((boff >> (sub * 16)) & 0xFFFFull) << 16);     \
      masks[(size_t)(b0 + sub) * TT + ((TBASE) + i)] = mk;                    \
    }                                                                         \
  }

  const uint32_t tbase =
      lds_addr32(&tile[0][0][0][0]) + (uint32_t)sub * 4096u + (uint32_t)f * 4u;

  K1_ISSUE(0);
  K1_WRITE(0);
  WAIT_LGKM(0);
  for (int g = 0; g < TT / 64; ++g) {
    if (g + 1 < TT / 64) K1_ISSUE(g + 1);
    const int buf = g & 1;
    const uint32_t caddr = tbase + (uint32_t)buf * 16384u;
    float va[8], vb[8];
    CHUNK_ISSUE(va, caddr);
#pragma unroll
    for (int c = 0; c < 8; ++c) {
      if (c < 7) {
        uint32_t an = caddr + (uint32_t)(c + 1) * 512u;
        if (c & 1) {
          CHUNK_ISSUE(va, an);
        } else {
          CHUNK_ISSUE(vb, an);
        }
        WAIT_LGKM(8);
      } else {
        WAIT_LGKM(0);
      }
      if (c & 1) {
        PROC8(vb, g * 64 + c * 8);
      } else {
        PROC8(va, g * 64 + c * 8);
      }
    }
    if (g + 1 < TT / 64) {
      K1_WRITE((g + 1) & 1);  // compiler inserts vmcnt for ld[] internally
      WAIT_LGKM(0);           // drain writes before next group's asm reads
    }
  }
#undef PROC8
#undef CHUNK_ISSUE
#undef K1_WRITE
#undef K1_ISSUE
}

// ---------------------------------------------------------------------------
// Kernel 2: serial SNN core, one wave per batch (256 blocks).
// lgkm domain = W2 slot reads ONLY (<=12 in flight; lgkmcnt cap is 15).
// vm domain   = W1t loads + mask prefetch + out stores (waits are vmcnt(0)).
// All sums keep the exact reference accumulation order (merged A-then-B
// extraction, sentinels add +0.0 at the tail of the 16 slots).
// ---------------------------------------------------------------------------
__global__ __launch_bounds__(64, 1) void snn_core4(
    const uint32_t* __restrict__ masks, const f32x2* __restrict__ w1t,
    const float* __restrict__ b1, const float* __restrict__ W2,
    const float* __restrict__ b2, const float* __restrict__ W3,
    const float* __restrict__ b3, float* __restrict__ out) {
  __shared__ f32x2 W2p[129 * 64];  // [j][l] = (W2[l][j], W2[64+l][j]); j=128 zero
  const int lane = threadIdx.x;
  const int b = blockIdx.x;

#pragma unroll 4
  for (int i = lane; i < 128 * 64; i += 64) {
    int l = i >> 7, j = i & 127;
    W2p[j * 64 + l] = f32x2{W2[l * 128 + j], W2[(64 + l) * 128 + j]};
  }
  W2p[128 * 64 + lane] = f32x2{0.f, 0.f};
  const f32x2 bias1 = {b1[lane], b1[64 + lane]};
  const f32x2 bias2 = {b2[lane], b2[64 + lane]};
  const float w30a = W3[lane], w30b = W3[64 + lane];
  const float w31a = W3[128 + lane], w31b = W3[192 + lane];
  const float b30 = b3[0], b31 = b3[1];
  __syncthreads();

  const uint32_t w2base = lds_addr32(&W2p[0]) + (uint32_t)lane * 8u;
  const uint32_t lane8 = (uint32_t)lane * 8u;
  float m1a = 0.f, m1b = 0.f, m2a = 0.f, m2b = 0.f, m3x = 0.f, m3y = 0.f;
  f32x2 cur1 = bias1;  // t=0: mask==0 -> 0-sum + bias (exact)
  f32x2 wL1[16];
  f32x2 w2v[16];
  const uint32_t* mrow = masks + (size_t)b * TT;
  float2* outv = (float2*)out;

// merged extraction of next ascending index over (a_:j 0-63, b_:j 64-127);
// sentinel 128 when exhausted. Wave-uniform SALU.
#define EXTRACT(J)                                                            \
  {                                                                           \
    bool av_ = (a_ != 0);                                                     \
    bool bv_ = (b_ != 0);                                                     \
    uint32_t ja_ = av_ ? (uint32_t)__builtin_ctzll(a_) : 0u;                  \
    uint32_t jb_ = bv_ ? 64u + (uint32_t)__builtin_ctzll(b_) : 128u;          \
    J = av_ ? ja_ : jb_;                                                      \
    u64 an_ = a_ & (a_ - 1);                                                  \
    u64 bn_ = b_ & (b_ - 1);                                                  \
    b_ = (!av_ && bv_) ? bn_ : b_;                                            \
    a_ = av_ ? an_ : a_;                                                      \
  }

#define STEP(MKN, T)                                                          \
  {                                                                           \
    /* LIF1 (cur1 computed at end of previous step) */                        \
    float n0 = __fadd_rn(__fmul_rn(0.9f, m1a), cur1.x);                       \
    float n1 = __fadd_rn(__fmul_rn(0.9f, m1b), cur1.y);                       \
    m1a = (m1a > 1.f) ? (n0 - 1.f) : n0;                                      \
    m1b = (m1b > 1.f) ? (n1 - 1.f) : n1;                                      \
    u64 a_ = __ballot(m1a > 1.f);                                             \
    u64 b_ = __ballot(m1b > 1.f);                                             \
    /* L2 issue: slots 0..11 (<=12 outstanding lgkm) */                       \
    _Pragma("unroll") for (int k = 0; k < 12; ++k) {                          \
      uint32_t j_;                                                            \
      EXTRACT(j_);                                                            \
      w2v[k] = ds_read_b64_at(w2base + (j_ << 9));                            \
    }                                                                         \
    /* L1(t+1) issue under L2 latency (vm domain) */                          \
    uint32_t mkn_ = __builtin_amdgcn_readfirstlane((int)(MKN));               \
    _Pragma("unroll") for (int k = 0; k < 16; ++k) {                          \
      uint32_t j1_ = mkn_ ? (uint32_t)__builtin_ctz(mkn_) : 32u;              \
      mkn_ &= mkn_ - 1u;                                                      \
      wL1[k] = glb_load_b64((j1_ << 9) + lane8, w1t);                         \
    }                                                                         \
    WAIT_LGKM(8); /* slots 0..3 landed (DS completes in order) */             \
    _Pragma("unroll") for (int k = 12; k < 16; ++k) {                         \
      uint32_t j_;                                                            \
      EXTRACT(j_);                                                            \
      w2v[k] = ds_read_b64_at(w2base + (j_ << 9));                            \
    }                                                                         \
    f32x2 c2 = {0.f, 0.f};                                                    \
    _Pragma("unroll") for (int k = 0; k < 4; ++k) c2 = pk_add(c2, w2v[k]);    \
    WAIT_LGKM(8);                                                             \
    _Pragma("unroll") for (int k = 4; k < 8; ++k) c2 = pk_add(c2, w2v[k]);    \
    WAIT_LGKM(4);                                                             \
    _Pragma("unroll") for (int k = 8; k < 12; ++k) c2 = pk_add(c2, w2v[k]);   \
    WAIT_LGKM(0);                                                             \
    _Pragma("unroll") for (int k = 12; k < 16; ++k) c2 = pk_add(c2, w2v[k]);  \
    /* rare tails (cnt>16), strict A-then-B ascending order */                \
    while (a_) {                                                              \
      uint32_t j_ = (uint32_t)__builtin_ctzll(a_);                            \
      a_ &= a_ - 1;                                                           \
      f32x2 tw = ds_read_b64_at(w2base + (j_ << 9));                          \
      WAIT_LGKM(0);                                                           \
      c2 = pk_add(c2, tw);                                                    \
    }                                                                         \
    while (b_) {                                                              \
      uint32_t j_ = 64u + (uint32_t)__builtin_ctzll(b_);                      \
      b_ &= b_ - 1;                                                           \
      f32x2 tw = ds_read_b64_at(w2base + (j_ << 9));                          \
      WAIT_LGKM(0);                                                           \
      c2 = pk_add(c2, tw);                                                    \
    }                                                                         \
    c2 = pk_add(c2, bias2);                                                   \
    /* LIF2 */                                                                \
    float u0 = __fadd_rn(__fmul_rn(0.9f, m2a), c2.x);                         \
    float u1 = __fadd_rn(__fmul_rn(0.9f, m2b), c2.y);                         \
    m2a = (m2a > 1.f) ? (u0 - 1.f) : u0;                                      \
    m2b = (m2b > 1.f) ? (u1 - 1.f) : u1;                                      \
    bool q0 = m2a > 1.f;                                                      \
    bool q1 = m2b > 1.f;                                                      \
    /* L3 */                                                                  \
    float p0 = (q0 ? w30a : 0.f) + (q1 ? w30b : 0.f);                         \
    float p1 = (q0 ? w31a : 0.f) + (q1 ? w31b : 0.f);                         \
    float c3x = wave_red_add63(p0) + b30;                                     \
    float c3y = wave_red_add63(p1) + b31;                                     \
    float e0 = __fadd_rn(__fmul_rn(0.9f, m3x), c3x);                          \
    float e1 = __fadd_rn(__fmul_rn(0.9f, m3y), c3y);                          \
    m3x = (m3x > 1.f) ? (e0 - 1.f) : e0;                                      \
    m3y = (m3y > 1.f) ? (e1 - 1.f) : e1;                                      \
    /* cur1 for next step (L1 loads landed during L2 consume) */              \
    WAIT_VM(0);                                                               \
    f32x2 s1_ = {0.f, 0.f};                                                   \
    _Pragma("unroll") for (int k = 0; k < 16; ++k) s1_ = pk_add(s1_, wL1[k]); \
    cur1 = pk_add(s1_, bias1);                                                \
    if (lane == 63) outv[(size_t)(T)*BB + b] = make_float2(m3x, m3y);         \
  }

  // mask prefetch: 4 steps/group via one asm dwordx4 (vm domain; every step's
  // WAIT_VM(0) guarantees the group's masks are resident well before use).
  u32x4 ca = glb_load_b128(0u, mrow);
  WAIT_VM(0);
  for (int t0 = 0; t0 < TT; t0 += 4) {
    uint32_t noff = (uint32_t)(((t0 + 4) & (TT - 1)) * 4);
    u32x4 na = glb_load_b128(noff, mrow);
    STEP(ca.y, t0 + 0);
    STEP(ca.z, t0 + 1);
    STEP(ca.w, t0 + 2);
    STEP(na.x, t0 + 3);
    ca = na;
  }
#undef STEP
#undef EXTRACT
}

extern "C" void kernel_launch(void* const* d_in, const int* in_sizes, int n_in,
                              void* d_out, int out_size, void* d_ws,
                              size_t ws_size, hipStream_t stream) {
  const float* x = (const float*)d_in[0];
  const float* W1 = (const float*)d_in[1];
  const float* b1 = (const float*)d_in[2];
  const float* W2 = (const float*)d_in[3];
  const float* b2 = (const float*)d_in[4];
  const float* W3 = (const float*)d_in[5];
  const float* b3 = (const float*)d_in[6];
  float* out = (float*)d_out;
  uint32_t* masks = (uint32_t*)d_ws;  // 4 MiB
  f32x2* w1t = (f32x2*)((char*)d_ws + (size_t)BB * TT * 4);  // +16.9 KiB

  snn_prep<<<1, 64, 0, stream>>>(W1, w1t);
  snn_encode<<<BB / 4, 64, 0, stream>>>(x, masks);
  snn_core4<<<BB, 64, 0, stream>>>(masks, w1t, b1, W2, b2, W3, b3, out);
}